// Round 2
// baseline (289.924 us; speedup 1.0000x reference)
//
#include <hip/hip_runtime.h>
#include <hip/hip_bf16.h>
#include <math.h>

typedef __attribute__((ext_vector_type(8))) short bfrag;   // 8 bf16 (16B)
typedef __attribute__((ext_vector_type(4))) float ffrag;   // mfma acc
typedef __attribute__((ext_vector_type(4))) float f4v;

#define C3 1536   // 3*H*D
#define QS 72     // q/k LDS row stride (shorts): 144B rows, 16B-aligned, bank-staggered
#define PS 24     // P LDS row stride (shorts): 48B rows

__device__ __forceinline__ unsigned short f2bf(float f) {
    unsigned u = __float_as_uint(f);
    return (unsigned short)((u + 0x7FFFu + ((u >> 16) & 1u)) >> 16);  // RNE
}
__device__ __forceinline__ float bf2f(unsigned short s) {
    return __uint_as_float(((unsigned)s) << 16);
}

// ---------------- kernel 1: cqkv (bf16 table) + pqkv (f32) + pq/pk bf16 table ----------------
__global__ __launch_bounds__(256) void precompute_kernel(
    const float* __restrict__ char_emb, const float* __restrict__ Wc, const float* __restrict__ bc,
    const float* __restrict__ Wp, const float* __restrict__ bp,
    unsigned short* __restrict__ cqkv, float* __restrict__ pqkv,
    unsigned short* __restrict__ pbf)
{
    const int b = blockIdx.x;
    const int t = threadIdx.x;
    if (b < 256) {                       // cqkv: 8 vocab rows per block
        __shared__ float semb[8][64];
        for (int idx = t; idx < 512; idx += 256)
            semb[idx >> 6][idx & 63] = char_emb[b * 512 + idx];
        __syncthreads();
        for (int cc = 0; cc < 6; ++cc) {
            const int c = t + cc * 256;
            float acc[8];
            const float bias = bc[c];
            #pragma unroll
            for (int r = 0; r < 8; ++r) acc[r] = bias;
            for (int dd = 0; dd < 64; ++dd) {
                const float wv = Wc[dd * C3 + c];
                #pragma unroll
                for (int r = 0; r < 8; ++r) acc[r] = fmaf(semb[r][dd], wv, acc[r]);
            }
            #pragma unroll
            for (int r = 0; r < 8; ++r)
                cqkv[(size_t)(b * 8 + r) * C3 + c] = f2bf(acc[r]);
        }
    } else {                             // pqkv: pos (double, matches numpy) @ Wp + bp
        __shared__ float spos[16][64];
        for (int idx = t; idx < 1024; idx += 256) {
            const int l = idx >> 6, d = idx & 63;
            const int f = d & 31;
            const double inv = pow(10000.0, -(double)f / 32.0);
            const double ph = (double)l * inv;
            spos[l][d] = (float)((d < 32) ? cos(ph) : sin(ph));
        }
        __syncthreads();
        for (int cc = 0; cc < 6; ++cc) {
            const int c = t + cc * 256;
            float acc[16];
            const float bias = bp[c];
            #pragma unroll
            for (int l = 0; l < 16; ++l) acc[l] = bias;
            for (int dd = 0; dd < 64; ++dd) {
                const float wv = Wp[dd * C3 + c];
                #pragma unroll
                for (int l = 0; l < 16; ++l) acc[l] = fmaf(spos[l][dd], wv, acc[l]);
            }
            #pragma unroll
            for (int l = 0; l < 16; ++l) pqkv[l * C3 + c] = acc[l];
            if (c < 1024) {              // pq/pk bf16 table: [(s*8+h)][l][d]
                #pragma unroll
                for (int l = 0; l < 16; ++l)
                    pbf[(c >> 6) * 1024 + l * 64 + (c & 63)] = f2bf(acc[l]);
            }
        }
    }
}

// ------- kernel 2: per-word fused attention + LN + pool + MLP (1 block = 1 word) -------
__global__ __launch_bounds__(512, 4) void attn_kernel(
    const unsigned short* __restrict__ cqkv, const float* __restrict__ pqkv,
    const unsigned short* __restrict__ pbf,
    const int* __restrict__ char_code,
    const float* __restrict__ gamma, const float* __restrict__ beta,
    const float* __restrict__ W1, const float* __restrict__ b1,
    const float* __restrict__ W2, const float* __restrict__ b2,
    float* __restrict__ xout)
{
    __shared__ __attribute__((aligned(16))) unsigned short sQc[8 * 16 * QS];  // raw cq (gathered)
    __shared__ __attribute__((aligned(16))) unsigned short sKc[8 * 16 * QS];  // raw ck (gathered)
    __shared__ __attribute__((aligned(16))) unsigned short sVt[8 * 1024];     // v=cv+pv, B-frag order + swizzle
    __shared__ __attribute__((aligned(16))) unsigned short sP[8 * 16 * PS];
    __shared__ __attribute__((aligned(16))) unsigned short sZero[8];
    __shared__ float sPool[8 * 64];
    __shared__ int   sCode[16];
    __shared__ float sWb[280];   // W1(128) b1(16) W2(128) b2(8)

    const int w = blockIdx.x;
    const int t = threadIdx.x;
    const int lane = t & 63;
    const int h = t >> 6;          // wave id = head
    const int quad = lane >> 4;
    const int n = lane & 15;

    if (t < 16) sCode[t] = char_code[w * 16 + t];
    if (t < 8) sZero[t] = 0;
    if (t < 128) sWb[t] = W1[t];
    else if (t < 144) sWb[t] = b1[t - 128];
    else if (t < 272) sWb[t] = W2[t - 144];
    else if (t < 280) sWb[t] = b2[t - 272];

    float gam[4], bet[4];
    #pragma unroll
    for (int dt = 0; dt < 4; ++dt) {
        gam[dt] = gamma[dt * 16 + n];
        bet[dt] = beta[dt * 16 + n];
    }
    __syncthreads();

    // ---- stage cq, ck (raw bf16 copies) and v = cv + pv for head h ----
    #pragma unroll
    for (int cc = 0; cc < 2; ++cc) {
        const int l = n;                         // char position
        const int d8 = quad + cc * 4;            // d-octet 0..7
        const int code = sCode[l];
        const size_t cbase = (size_t)code * C3 + h * 64 + d8 * 8;
        *(bfrag*)(sQc + (h * 16 + l) * QS + d8 * 8) = *(const bfrag*)(cqkv + cbase);
        *(bfrag*)(sKc + (h * 16 + l) * QS + d8 * 8) = *(const bfrag*)(cqkv + cbase + 512);
        const bfrag cb = *(const bfrag*)(cqkv + cbase + 1024);
        const int pbase = l * C3 + h * 64 + d8 * 8 + 1024;
        const f4v pa = *(const f4v*)(pqkv + pbase);
        const f4v pb = *(const f4v*)(pqkv + pbase + 4);
        #pragma unroll
        for (int j = 0; j < 8; ++j) {
            const float f = bf2f((unsigned short)cb[j]) + ((j < 4) ? pa[j] : pb[j - 4]);
            const int d = d8 * 8 + j;
            const int e = h * 1024 + ((d >> 4) * 2 + (l >> 3)) * 128
                        + ((d & 15) ^ ((l >> 3) << 2)) * 8 + (l & 7);
            sVt[e] = f2bf(f);
        }
    }
    __syncthreads();

    int nv = 0;
    #pragma unroll
    for (int l2 = 0; l2 < 16; ++l2) nv += (sCode[l2] != 0) ? 1 : 0;

    // ---- S[i][j] = cq_i·ck_j + cq_i·pk_j + pq_i·pk_j + ck_i·pq_j ----
    // (A and B fragment read patterns are identical: row = lane&15, k = quad*8+j)
    ffrag accS = {0.f, 0.f, 0.f, 0.f};
    {
        const unsigned short* qrow = sQc + (h * 16 + n) * QS;
        const unsigned short* krow = sKc + (h * 16 + n) * QS;
        const unsigned short* pqg = pbf + h * 1024 + n * 64;          // pq head h
        const unsigned short* pkg = pbf + (8 + h) * 1024 + n * 64;    // pk head h
        #pragma unroll
        for (int ds_ = 0; ds_ < 2; ++ds_) {
            const int off = quad * 8 + ds_ * 32;
            const bfrag cqF = *(const bfrag*)(qrow + off);
            const bfrag ckF = *(const bfrag*)(krow + off);
            const bfrag pqF = *(const bfrag*)(pqg + off);
            const bfrag pkF = *(const bfrag*)(pkg + off);
            accS = __builtin_amdgcn_mfma_f32_16x16x32_bf16(cqF, ckF, accS, 0, 0, 0);
            accS = __builtin_amdgcn_mfma_f32_16x16x32_bf16(cqF, pkF, accS, 0, 0, 0);
            accS = __builtin_amdgcn_mfma_f32_16x16x32_bf16(pqF, pkF, accS, 0, 0, 0);
            accS = __builtin_amdgcn_mfma_f32_16x16x32_bf16(ckF, pqF, accS, 0, 0, 0);
        }
    }

    // ---- masked softmax over j (columns spread over the 16 lanes of each quad) ----
    const bool keyvalid = (sCode[n] != 0);
    float sv[4], mx[4], pr[4], sm[4];
    #pragma unroll
    for (int r = 0; r < 4; ++r) sv[r] = keyvalid ? accS[r] * 0.125f : -1e30f;
    #pragma unroll
    for (int r = 0; r < 4; ++r) mx[r] = sv[r];
    #pragma unroll
    for (int xm = 1; xm <= 8; xm <<= 1) {
        #pragma unroll
        for (int r = 0; r < 4; ++r) mx[r] = fmaxf(mx[r], __shfl_xor(mx[r], xm));
    }
    #pragma unroll
    for (int r = 0; r < 4; ++r) { pr[r] = expf(sv[r] - mx[r]); sm[r] = pr[r]; }
    #pragma unroll
    for (int xm = 1; xm <= 8; xm <<= 1) {
        #pragma unroll
        for (int r = 0; r < 4; ++r) sm[r] += __shfl_xor(sm[r], xm);
    }
    #pragma unroll
    for (int r = 0; r < 4; ++r)
        sP[(h * 16 + quad * 4 + r) * PS + n] = f2bf(pr[r] / sm[r]);

    __syncthreads();

    // ---- O = P V (K=16 zero-padded to 32 via sZero for quads 2,3) ----
    ffrag accO[4];
    #pragma unroll
    for (int dt = 0; dt < 4; ++dt) { ffrag z = {0.f,0.f,0.f,0.f}; accO[dt] = z; }
    {
        const unsigned short* pp = (quad < 2) ? (sP + (h * 16 + n) * PS + quad * 8) : sZero;
        const bfrag ap = *(const bfrag*)pp;
        #pragma unroll
        for (int dt = 0; dt < 4; ++dt) {
            const unsigned short* vp = (quad < 2)
                ? (sVt + h * 1024 + (dt * 2 + quad) * 128 + (n ^ (quad << 2)) * 8)
                : sZero;
            const bfrag bv = *(const bfrag*)vp;
            accO[dt] = __builtin_amdgcn_mfma_f32_16x16x32_bf16(ap, bv, accO[dt], 0, 0, 0);
        }
    }

    // ---- LayerNorm over D + masked pool over i ----
    float ps1[4], ps2[4];
    #pragma unroll
    for (int r = 0; r < 4; ++r) {
        ps1[r] = accO[0][r] + accO[1][r] + accO[2][r] + accO[3][r];
        ps2[r] = accO[0][r]*accO[0][r] + accO[1][r]*accO[1][r]
               + accO[2][r]*accO[2][r] + accO[3][r]*accO[3][r];
    }
    #pragma unroll
    for (int xm = 1; xm <= 8; xm <<= 1) {
        #pragma unroll
        for (int r = 0; r < 4; ++r) {
            ps1[r] += __shfl_xor(ps1[r], xm);
            ps2[r] += __shfl_xor(ps2[r], xm);
        }
    }
    float pool[4] = {0.f, 0.f, 0.f, 0.f};
    #pragma unroll
    for (int r = 0; r < 4; ++r) {
        const float mu   = ps1[r] * 0.015625f;
        const float var  = fmaxf(ps2[r] * 0.015625f - mu * mu, 0.f);
        const float rstd = rsqrtf(var + 1e-5f);
        const float iv = (sCode[quad * 4 + r] != 0) ? 1.f : 0.f;
        #pragma unroll
        for (int dt = 0; dt < 4; ++dt)
            pool[dt] += iv * fmaf((accO[dt][r] - mu) * rstd, gam[dt], bet[dt]);
    }
    #pragma unroll
    for (int xm = 16; xm <= 32; xm <<= 1) {
        #pragma unroll
        for (int dt = 0; dt < 4; ++dt) pool[dt] += __shfl_xor(pool[dt], xm);
    }
    if (quad == 0) {
        const float invnv = 1.f / (float)nv;
        #pragma unroll
        for (int dt = 0; dt < 4; ++dt) sPool[h * 64 + dt * 16 + n] = pool[dt] * invnv;
    }
    __syncthreads();

    // ---- MLP: relu(pooled@W1+b1)@W2+b2, thread t -> (d=t>>3, o=t&7) ----
    {
        const int d = t >> 3, o = t & 7;
        float pl[8];
        #pragma unroll
        for (int hh = 0; hh < 8; ++hh) pl[hh] = sPool[hh * 64 + d];
        float acc = sWb[272 + o];
        #pragma unroll
        for (int c = 0; c < 16; ++c) {
            float hs = sWb[128 + c];
            #pragma unroll
            for (int hh = 0; hh < 8; ++hh) hs = fmaf(pl[hh], sWb[hh * 16 + c], hs);
            hs = fmaxf(hs, 0.f);
            acc = fmaf(hs, sWb[144 + c * 8 + o], acc);
        }
        xout[(size_t)w * 512 + t] = acc;
    }
}

// ---------------- kernel 3a: exclusive prefix of n_words (int32!) ----------------
__global__ __launch_bounds__(256) void scan_kernel(const int* __restrict__ n_words,
                                                   int* __restrict__ offsets)
{
    __shared__ int part[256];
    const int t = threadIdx.x;
    int loc[8];
    int s = 0;
    #pragma unroll
    for (int r = 0; r < 8; ++r) { loc[r] = s; s += n_words[t * 8 + r]; }
    part[t] = s;
    __syncthreads();
    for (int off = 1; off < 256; off <<= 1) {
        const int u = (t >= off) ? part[t - off] : 0;
        __syncthreads();
        part[t] += u;
        __syncthreads();
    }
    const int excl = (t == 0) ? 0 : part[t - 1];
    #pragma unroll
    for (int r = 0; r < 8; ++r) offsets[t * 8 + r] = excl + loc[r];
}

// ---------------- kernel 3b: per-name word average ----------------
__global__ __launch_bounds__(128) void name_avg_kernel(
    const float* __restrict__ xws, const int* __restrict__ word_code,
    const int* __restrict__ n_words, const int* __restrict__ offsets,
    float* __restrict__ out)
{
    const int nm = blockIdx.x;
    const int t = threadIdx.x;
    const int off = offsets[nm];
    const int cnt = n_words[nm];
    const float inv = 1.f / (float)cnt;
    #pragma unroll
    for (int e0 = 0; e0 < 4; ++e0) {
        const int e = e0 * 128 + t;
        float acc = 0.f;
        for (int r = 0; r < cnt; ++r)
            acc += xws[(size_t)word_code[off + r] * 512 + e];
        out[(size_t)nm * 512 + e] = acc * inv;
    }
}

extern "C" void kernel_launch(void* const* d_in, const int* in_sizes, int n_in,
                              void* d_out, int out_size, void* d_ws, size_t ws_size,
                              hipStream_t stream) {
    (void)in_sizes; (void)n_in; (void)out_size; (void)ws_size;
    const float* char_emb = (const float*)d_in[0];
    const float* Wc    = (const float*)d_in[1];
    const float* bc    = (const float*)d_in[2];
    const float* Wp    = (const float*)d_in[3];
    const float* bp    = (const float*)d_in[4];
    const float* gamma = (const float*)d_in[5];
    const float* beta  = (const float*)d_in[6];
    const float* W1    = (const float*)d_in[7];
    const float* b1    = (const float*)d_in[8];
    const float* W2    = (const float*)d_in[9];
    const float* b2    = (const float*)d_in[10];
    const int* char_code = (const int*)d_in[11];
    const int* word_code = (const int*)d_in[12];
    const int* n_words   = (const int*)d_in[13];   // harness passes ALL ints as int32

    char* ws = (char*)d_ws;
    unsigned short* cqkv = (unsigned short*)ws;                        //  6,291,456 B
    float* pqkv = (float*)(ws + 6291456);                              //     98,304 B
    unsigned short* pbf = (unsigned short*)(ws + 6291456 + 98304);     //     32,768 B
    float* xws  = (float*)(ws + 6291456 + 98304 + 32768);              // 16,777,216 B
    int* offsets = (int*)(ws + 6291456 + 98304 + 32768 + 16777216);    //      8,192 B
    float* out = (float*)d_out;

    precompute_kernel<<<257, 256, 0, stream>>>(char_emb, Wc, bc, Wp, bp, cqkv, pqkv, pbf);
    attn_kernel<<<8192, 512, 0, stream>>>(cqkv, pqkv, pbf, char_code, gamma, beta,
                                          W1, b1, W2, b2, xws);
    scan_kernel<<<1, 256, 0, stream>>>(n_words, offsets);
    name_avg_kernel<<<2048, 128, 0, stream>>>(xws, word_code, n_words, offsets, out);
}